// Round 1
// baseline (15620.676 us; speedup 1.0000x reference)
//
#include <hip/hip_runtime.h>

#define D 128

__device__ __forceinline__ void fadd(float* p, float v) { unsafeAtomicAdd(p, v); }

// ---- degree / norm kernels ----
__global__ void k_deg(const int* __restrict__ u, const int* __restrict__ s,
                      float* udeg, float* sdeg, int E) {
  int e = blockIdx.x * blockDim.x + threadIdx.x;
  if (e < E) {
    fadd(&udeg[u[e]], 1.0f);
    fadd(&sdeg[s[e]], 1.0f);
  }
}

__global__ void k_invdiv(const int* __restrict__ u, const int* __restrict__ s,
                         const float* __restrict__ udeg, const float* __restrict__ sdeg,
                         float* __restrict__ inv, int E) {
  int e = blockIdx.x * blockDim.x + threadIdx.x;
  if (e < E) inv[e] = rsqrtf(udeg[u[e]] * sdeg[s[e]]);
}

__global__ void k_degsp(const int* __restrict__ dst, const float* __restrict__ ew,
                        float* deg, int E) {
  int e = blockIdx.x * blockDim.x + threadIdx.x;
  if (e < E) fadd(&deg[dst[e]], ew[e]);
}

__global__ void k_dinv(float* deg, int n) {
  int i = blockIdx.x * blockDim.x + threadIdx.x;
  if (i < n) {
    float d = deg[i];
    deg[i] = d > 0.f ? rsqrtf(fmaxf(d, 1e-12f)) : 0.f;
  }
}

// ---- GEMM: Y[rows x 128] = X[rows x 128] @ W[128 x 128], W staged in LDS ----
__global__ __launch_bounds__(128) void k_gemm(const float* __restrict__ X,
                                              const float* __restrict__ W,
                                              float* __restrict__ Y, int rows) {
  __shared__ float Wl[D * D];  // 64 KB
  int tid = threadIdx.x;       // 0..127 -> output column
  const float4* W4 = (const float4*)W;
  float4* Wl4 = (float4*)Wl;
  for (int i = tid; i < D * D / 4; i += 128) Wl4[i] = W4[i];
  __syncthreads();
  int r0 = blockIdx.x * 64;
  int rend = r0 + 64 < rows ? r0 + 64 : rows;
  for (int r = r0; r < rend; ++r) {
    const float4* xr = (const float4*)(X + (size_t)r * D);
    float acc = 0.f;
#pragma unroll
    for (int k4 = 0; k4 < D / 4; ++k4) {
      float4 xv = xr[k4];
      acc += xv.x * Wl[(k4 * 4 + 0) * D + tid];
      acc += xv.y * Wl[(k4 * 4 + 1) * D + tid];
      acc += xv.z * Wl[(k4 * 4 + 2) * D + tid];
      acc += xv.w * Wl[(k4 * 4 + 3) * D + tid];
    }
    Y[(size_t)r * D + tid] = acc;
  }
}

// ---- fused bipartite scatter: one 32-lane group per edge, float4 per lane ----
__global__ void k_prop_scatter(const int* __restrict__ u, const int* __restrict__ s,
                               const float* __restrict__ w,
                               const float* __restrict__ sx, const float* __restrict__ ux,
                               float* un, float* sn, int E) {
  int g = blockIdx.x * blockDim.x + threadIdx.x;
  int e = g >> 5, lane = g & 31;
  if (e >= E) return;
  int ue = u[e], se = s[e];
  float we = w[e];
  float4 sv = ((const float4*)(sx + (size_t)se * D))[lane];
  float4 uv = ((const float4*)(ux + (size_t)ue * D))[lane];
  float* up = un + (size_t)ue * D + lane * 4;
  float* sp = sn + (size_t)se * D + lane * 4;
  fadd(up + 0, sv.x * we); fadd(up + 1, sv.y * we);
  fadd(up + 2, sv.z * we); fadd(up + 3, sv.w * we);
  fadd(sp + 0, uv.x * we); fadd(sp + 1, uv.y * we);
  fadd(sp + 2, uv.z * we); fadd(sp + 3, uv.w * we);
}

// ---- GCN scatter: out[dst] += scale * dinv[src]*ew*dinv[dst] * xw[src] ----
__global__ void k_gcn_scatter(const int* __restrict__ src, const int* __restrict__ dst,
                              const float* __restrict__ ew, const float* __restrict__ dinv,
                              const float* __restrict__ xw, float* out, float scale, int E) {
  int g = blockIdx.x * blockDim.x + threadIdx.x;
  int e = g >> 5, lane = g & 31;
  if (e >= E) return;
  int se = src[e], de = dst[e];
  float nrm = dinv[se] * ew[e] * dinv[de] * scale;
  float4 v = ((const float4*)(xw + (size_t)se * D))[lane];
  float* o = out + (size_t)de * D + lane * 4;
  fadd(o + 0, v.x * nrm); fadd(o + 1, v.y * nrm);
  fadd(o + 2, v.z * nrm); fadd(o + 3, v.w * nrm);
}

// ---- elementwise helpers (float4 granularity) ----
__global__ void k_add(float* __restrict__ dst, const float* __restrict__ src, int n4) {
  int i = blockIdx.x * blockDim.x + threadIdx.x;
  if (i < n4) {
    float4 a = ((float4*)dst)[i];
    float4 b = ((const float4*)src)[i];
    a.x += b.x; a.y += b.y; a.z += b.z; a.w += b.w;
    ((float4*)dst)[i] = a;
  }
}

__global__ void k_scale(float* __restrict__ dst, float f, int n4) {
  int i = blockIdx.x * blockDim.x + threadIdx.x;
  if (i < n4) {
    float4 a = ((float4*)dst)[i];
    a.x *= f; a.y *= f; a.z *= f; a.w *= f;
    ((float4*)dst)[i] = a;
  }
}

extern "C" void kernel_launch(void* const* d_in, const int* in_sizes, int n_in,
                              void* d_out, int out_size, void* d_ws, size_t ws_size,
                              hipStream_t stream) {
  const float* spot_emb = (const float*)d_in[0];
  const float* user_emb = (const float*)d_in[1];
  const float* W1 = (const float*)d_in[2];
  const float* W2 = (const float*)d_in[3];
  const float* W3 = (const float*)d_in[4];
  const float* ew1 = (const float*)d_in[5];
  const float* ew2 = (const float*)d_in[6];
  const float* ew3 = (const float*)d_in[7];
  const int* us = (const int*)d_in[8];
  const int* ei1 = (const int*)d_in[9];
  const int* ei2 = (const int*)d_in[10];
  const int* ei3 = (const int*)d_in[11];

  const int M = in_sizes[0] / D;
  const int N = in_sizes[1] / D;
  const int EUS = in_sizes[8] / 2;
  const int ES1 = in_sizes[9] / 2;
  const int ES2 = in_sizes[10] / 2;
  const int ES3 = in_sizes[11] / 2;

  const int* uu = us;        // user index per edge
  const int* ss = us + EUS;  // spot index per edge

  const size_t MD = (size_t)M * D, ND = (size_t)N * D;
  auto al = [](size_t x) { return (x + 63) & ~(size_t)63; };
  float* ws = (float*)d_ws;
  float* w_udeg = ws; ws += al(N);
  float* w_sdeg = ws; ws += al(M);
  float* w_dinv = ws; ws += al(M);
  float* w_inv  = ws; ws += al(EUS);
  float* w_xw   = ws; ws += MD;
  float* w_sA   = ws; ws += MD;
  float* w_sB   = ws; ws += MD;
  float* w_uA   = ws; ws += ND;
  float* w_uB   = ws; ws += ND;

  float* out = (float*)d_out;
  float* o_so1 = out;
  float* o_uo1 = o_so1 + MD;
  float* o_so2 = o_uo1 + ND;
  float* o_uo2 = o_so2 + MD;
  float* o_so3 = o_uo2 + ND;
  float* o_uo3 = o_so3 + MD;

  auto cpy = [&](float* dst, const float* src, size_t n) {
    hipMemcpyAsync(dst, src, n * sizeof(float), hipMemcpyDeviceToDevice, stream);
  };
  auto zero = [&](float* p, size_t n) { hipMemsetAsync(p, 0, n * sizeof(float), stream); };

  const int B = 256;
  const int gM4 = (int)((MD / 4 + B - 1) / B), gN4 = (int)((ND / 4 + B - 1) / B);
  const int gPS = (int)(((size_t)EUS * 32 + B - 1) / B);

  // degrees + per-edge inv_div
  zero(w_udeg, N); zero(w_sdeg, M);
  k_deg<<<(EUS + B - 1) / B, B, 0, stream>>>(uu, ss, w_udeg, w_sdeg, EUS);
  k_invdiv<<<(EUS + B - 1) / B, B, 0, stream>>>(uu, ss, w_udeg, w_sdeg, w_inv, EUS);

  // ---- propagation 2 (raw embeddings); acc lives in so2/uo2 ----
  cpy(w_sA, spot_emb, MD); cpy(w_uA, user_emb, ND);
  cpy(o_so2, spot_emb, MD); cpy(o_uo2, user_emb, ND);
  float *cs = w_sA, *cu = w_uA, *ns = w_sB, *nu = w_uB;
  for (int l = 0; l < 3; ++l) {
    zero(ns, MD); zero(nu, ND);
    k_prop_scatter<<<gPS, B, 0, stream>>>(uu, ss, w_inv, cs, cu, nu, ns, EUS);
    k_add<<<gM4, B, 0, stream>>>(o_so2, ns, (int)(MD / 4));
    k_add<<<gN4, B, 0, stream>>>(o_uo2, nu, (int)(ND / 4));
    float* t = cs; cs = ns; ns = t; t = cu; cu = nu; nu = t;
  }
  k_scale<<<gM4, B, 0, stream>>>(o_so2, 0.25f, (int)(MD / 4));
  k_scale<<<gN4, B, 0, stream>>>(o_uo2, 0.25f, (int)(ND / 4));
  cpy(o_so3, o_so2, MD); cpy(o_uo3, o_uo2, ND);  // p_s, p_u
  float* fin_s = cs;  // post-loop spot_x2

  // ---- GCN branch 2: so2 += cat2/4 ----
  k_gemm<<<(M + 63) / 64, 128, 0, stream>>>(spot_emb, W2, w_xw, M);
  zero(w_dinv, M);
  k_degsp<<<(ES2 + B - 1) / B, B, 0, stream>>>(ei2 + ES2, ew2, w_dinv, ES2);
  k_dinv<<<(M + B - 1) / B, B, 0, stream>>>(w_dinv, M);
  k_gcn_scatter<<<(int)(((size_t)ES2 * 32 + B - 1) / B), B, 0, stream>>>(
      ei2, ei2 + ES2, ew2, w_dinv, w_xw, o_so2, 0.25f, ES2);

  // ---- GCN branch 3: so3 += cat3/4 (uses fin_s) ----
  k_gemm<<<(M + 63) / 64, 128, 0, stream>>>(fin_s, W3, w_xw, M);
  zero(w_dinv, M);
  k_degsp<<<(ES3 + B - 1) / B, B, 0, stream>>>(ei3 + ES3, ew3, w_dinv, ES3);
  k_dinv<<<(M + B - 1) / B, B, 0, stream>>>(w_dinv, M);
  k_gcn_scatter<<<(int)(((size_t)ES3 * 32 + B - 1) / B), B, 0, stream>>>(
      ei3, ei3 + ES3, ew3, w_dinv, w_xw, o_so3, 0.25f, ES3);

  // ---- GCN branch 1 (cat1 into spot_x0) + propagation 1 ----
  k_gemm<<<(M + 63) / 64, 128, 0, stream>>>(spot_emb, W1, w_xw, M);
  zero(w_dinv, M);
  k_degsp<<<(ES1 + B - 1) / B, B, 0, stream>>>(ei1 + ES1, ew1, w_dinv, ES1);
  k_dinv<<<(M + B - 1) / B, B, 0, stream>>>(w_dinv, M);
  cpy(w_sA, spot_emb, MD);  // spot_x0 = spot_emb ...
  k_gcn_scatter<<<(int)(((size_t)ES1 * 32 + B - 1) / B), B, 0, stream>>>(
      ei1, ei1 + ES1, ew1, w_dinv, w_xw, w_sA, 1.0f, ES1);  // ... + cat1
  cpy(w_uA, user_emb, ND);
  cpy(o_so1, w_sA, MD); cpy(o_uo1, user_emb, ND);
  cs = w_sA; cu = w_uA; ns = w_sB; nu = w_uB;
  for (int l = 0; l < 3; ++l) {
    zero(ns, MD); zero(nu, ND);
    k_prop_scatter<<<gPS, B, 0, stream>>>(uu, ss, w_inv, cs, cu, nu, ns, EUS);
    k_add<<<gM4, B, 0, stream>>>(o_so1, ns, (int)(MD / 4));
    k_add<<<gN4, B, 0, stream>>>(o_uo1, nu, (int)(ND / 4));
    float* t = cs; cs = ns; ns = t; t = cu; cu = nu; nu = t;
  }
  k_scale<<<gM4, B, 0, stream>>>(o_so1, 0.25f, (int)(MD / 4));
  k_scale<<<gN4, B, 0, stream>>>(o_uo1, 0.25f, (int)(ND / 4));
}

// Round 2
// 2040.994 us; speedup vs baseline: 7.6535x; 7.6535x over previous
//
#include <hip/hip_runtime.h>

#define D 128

__device__ __forceinline__ void fadd(float* p, float v) { unsafeAtomicAdd(p, v); }

// ---- degree / norm kernels ----
__global__ void k_deg(const int* __restrict__ u, const int* __restrict__ s,
                      float* udeg, float* sdeg, int E) {
  int e = blockIdx.x * blockDim.x + threadIdx.x;
  if (e < E) {
    fadd(&udeg[u[e]], 1.0f);
    fadd(&sdeg[s[e]], 1.0f);
  }
}

__global__ void k_invdiv(const int* __restrict__ u, const int* __restrict__ s,
                         const float* __restrict__ udeg, const float* __restrict__ sdeg,
                         float* __restrict__ inv, int E) {
  int e = blockIdx.x * blockDim.x + threadIdx.x;
  if (e < E) inv[e] = rsqrtf(udeg[u[e]] * sdeg[s[e]]);
}

__global__ void k_degsp(const int* __restrict__ dst, const float* __restrict__ ew,
                        float* deg, int E) {
  int e = blockIdx.x * blockDim.x + threadIdx.x;
  if (e < E) fadd(&deg[dst[e]], ew[e]);
}

__global__ void k_dinv(float* deg, int n) {
  int i = blockIdx.x * blockDim.x + threadIdx.x;
  if (i < n) {
    float d = deg[i];
    deg[i] = d > 0.f ? rsqrtf(fmaxf(d, 1e-12f)) : 0.f;
  }
}

__global__ void k_cnt(const int* __restrict__ dst, float* cnt, int E) {
  int e = blockIdx.x * blockDim.x + threadIdx.x;
  if (e < E) fadd(&cnt[dst[e]], 1.0f);
}

// ---- exclusive prefix sum of float counts -> int row_ptr (n <= ~44k) ----
__global__ __launch_bounds__(1024) void k_scan(const float* __restrict__ cnt,
                                               int* __restrict__ rp, int n) {
  __shared__ int part[1024];
  int tid = threadIdx.x;
  int chunk = (n + 1023) / 1024;
  int lo = tid * chunk;
  int hi = lo + chunk < n ? lo + chunk : n;
  if (lo > n) lo = n;
  if (hi < lo) hi = lo;
  int s = 0;
  for (int i = lo; i < hi; ++i) s += (int)cnt[i];
  part[tid] = s;
  __syncthreads();
  for (int off = 1; off < 1024; off <<= 1) {
    int v = tid >= off ? part[tid - off] : 0;
    __syncthreads();
    part[tid] += v;
    __syncthreads();
  }
  int excl = tid == 0 ? 0 : part[tid - 1];
  for (int i = lo; i < hi; ++i) {
    rp[i] = excl;
    excl += (int)cnt[i];
  }
  if (hi == n) rp[n] = excl;
}

// ---- CSR fill: bipartite (both directions at once) ----
__global__ void k_fill_bip(const int* __restrict__ u, const int* __restrict__ s,
                           const float* __restrict__ inv,
                           const int* __restrict__ rp_u, const int* __restrict__ rp_s,
                           int* cur_u, int* cur_s,
                           int* __restrict__ ue_s, float* __restrict__ ue_w,
                           int* __restrict__ se_u, float* __restrict__ se_w, int E) {
  int e = blockIdx.x * blockDim.x + threadIdx.x;
  if (e >= E) return;
  int ui = u[e], si = s[e];
  float w = inv[e];
  int p = rp_u[ui] + atomicAdd(&cur_u[ui], 1);
  ue_s[p] = si; ue_w[p] = w;
  int q = rp_s[si] + atomicAdd(&cur_s[si], 1);
  se_u[q] = ui; se_w[q] = w;
}

// ---- CSR fill: GCN graph, bucketed by dst; store ew*dinv[src] ----
__global__ void k_fill_gcn(const int* __restrict__ src, const int* __restrict__ dst,
                           const float* __restrict__ ew, const float* __restrict__ dinv,
                           const int* __restrict__ rp, int* cur,
                           int* __restrict__ esrc, float* __restrict__ ewn, int E) {
  int e = blockIdx.x * blockDim.x + threadIdx.x;
  if (e >= E) return;
  int de = dst[e];
  int p = rp[de] + atomicAdd(&cur[de], 1);
  esrc[p] = src[e];
  ewn[p] = ew[e] * dinv[src[e]];
}

// ---- fused bipartite layer: gather both directions + acc update (+final scale)
__global__ void k_prop_gather(const int* __restrict__ rp_u, const int* __restrict__ ue_s,
                              const float* __restrict__ ue_w,
                              const int* __restrict__ rp_s, const int* __restrict__ se_u,
                              const float* __restrict__ se_w,
                              const float* __restrict__ sx, const float* __restrict__ ux,
                              float* __restrict__ un, float* __restrict__ sn,
                              float* __restrict__ uacc, float* __restrict__ sacc,
                              float fs, int N, int M) {
  int g = blockIdx.x * blockDim.x + threadIdx.x;
  int row = g >> 5, lane = g & 31;
  const int* rp; const int* ei; const float* ew; const float* src;
  float* dst; float* acc; int r;
  if (row < N) { rp = rp_u; ei = ue_s; ew = ue_w; src = sx; dst = un; acc = uacc; r = row; }
  else if (row < N + M) { rp = rp_s; ei = se_u; ew = se_w; src = ux; dst = sn; acc = sacc; r = row - N; }
  else return;
  int beg = rp[r], end = rp[r + 1];
  float4 sum = make_float4(0.f, 0.f, 0.f, 0.f);
  for (int i = beg; i < end; ++i) {
    int sr = ei[i];
    float w = ew[i];
    float4 v = ((const float4*)(src + (size_t)sr * D))[lane];
    sum.x = fmaf(w, v.x, sum.x); sum.y = fmaf(w, v.y, sum.y);
    sum.z = fmaf(w, v.z, sum.z); sum.w = fmaf(w, v.w, sum.w);
  }
  ((float4*)(dst + (size_t)r * D))[lane] = sum;
  float4* ap = (float4*)(acc + (size_t)r * D) + lane;
  float4 a = *ap;
  a.x = (a.x + sum.x) * fs; a.y = (a.y + sum.y) * fs;
  a.z = (a.z + sum.z) * fs; a.w = (a.w + sum.w) * fs;
  *ap = a;
}

// ---- GCN gather: out[row] += scale*dinv[row] * sum_e ewn * xw[src] ----
__global__ void k_gcn_gather(const int* __restrict__ rp, const int* __restrict__ esrc,
                             const float* __restrict__ ewn, const float* __restrict__ dinv,
                             const float* __restrict__ xw, float* __restrict__ out,
                             float scale, int M) {
  int g = blockIdx.x * blockDim.x + threadIdx.x;
  int row = g >> 5, lane = g & 31;
  if (row >= M) return;
  int beg = rp[row], end = rp[row + 1];
  float4 sum = make_float4(0.f, 0.f, 0.f, 0.f);
  for (int i = beg; i < end; ++i) {
    int sr = esrc[i];
    float w = ewn[i];
    float4 v = ((const float4*)(xw + (size_t)sr * D))[lane];
    sum.x = fmaf(w, v.x, sum.x); sum.y = fmaf(w, v.y, sum.y);
    sum.z = fmaf(w, v.z, sum.z); sum.w = fmaf(w, v.w, sum.w);
  }
  float sc = dinv[row] * scale;
  float4* op = (float4*)(out + (size_t)row * D) + lane;
  float4 o = *op;
  o.x = fmaf(sc, sum.x, o.x); o.y = fmaf(sc, sum.y, o.y);
  o.z = fmaf(sc, sum.z, o.z); o.w = fmaf(sc, sum.w, o.w);
  *op = o;
}

// ---- GEMM: Y[rows x 128] = X[rows x 128] @ W[128 x 128], W staged in LDS ----
__global__ __launch_bounds__(128) void k_gemm(const float* __restrict__ X,
                                              const float* __restrict__ W,
                                              float* __restrict__ Y, int rows) {
  __shared__ float Wl[D * D];  // 64 KB
  int tid = threadIdx.x;       // 0..127 -> output column
  const float4* W4 = (const float4*)W;
  float4* Wl4 = (float4*)Wl;
  for (int i = tid; i < D * D / 4; i += 128) Wl4[i] = W4[i];
  __syncthreads();
  int r0 = blockIdx.x * 64;
  int rend = r0 + 64 < rows ? r0 + 64 : rows;
  for (int r = r0; r < rend; ++r) {
    const float4* xr = (const float4*)(X + (size_t)r * D);
    float acc = 0.f;
#pragma unroll
    for (int k4 = 0; k4 < D / 4; ++k4) {
      float4 xv = xr[k4];
      acc += xv.x * Wl[(k4 * 4 + 0) * D + tid];
      acc += xv.y * Wl[(k4 * 4 + 1) * D + tid];
      acc += xv.z * Wl[(k4 * 4 + 2) * D + tid];
      acc += xv.w * Wl[(k4 * 4 + 3) * D + tid];
    }
    Y[(size_t)r * D + tid] = acc;
  }
}

extern "C" void kernel_launch(void* const* d_in, const int* in_sizes, int n_in,
                              void* d_out, int out_size, void* d_ws, size_t ws_size,
                              hipStream_t stream) {
  const float* spot_emb = (const float*)d_in[0];
  const float* user_emb = (const float*)d_in[1];
  const float* W1 = (const float*)d_in[2];
  const float* W2 = (const float*)d_in[3];
  const float* W3 = (const float*)d_in[4];
  const float* ew1 = (const float*)d_in[5];
  const float* ew2 = (const float*)d_in[6];
  const float* ew3 = (const float*)d_in[7];
  const int* us = (const int*)d_in[8];
  const int* ei1 = (const int*)d_in[9];
  const int* ei2 = (const int*)d_in[10];
  const int* ei3 = (const int*)d_in[11];

  const int M = in_sizes[0] / D;
  const int N = in_sizes[1] / D;
  const int EUS = in_sizes[8] / 2;
  const int ES1 = in_sizes[9] / 2;
  const int ES2 = in_sizes[10] / 2;
  const int ES3 = in_sizes[11] / 2;
  const int ESmax = ES1 > ES2 ? (ES1 > ES3 ? ES1 : ES3) : (ES2 > ES3 ? ES2 : ES3);

  const int* uu = us;        // user index per edge
  const int* ss = us + EUS;  // spot index per edge

  const size_t MD = (size_t)M * D, ND = (size_t)N * D;
  auto al = [](size_t x) { return (x + 63) & ~(size_t)63; };
  float* ws = (float*)d_ws;
  auto take = [&](size_t n) { float* p = ws; ws += al(n); return p; };

  float* w_udeg = take(N);
  float* w_sdeg = take(M);
  float* w_dinv = take(M);          // GCN dinv (reused per graph)
  float* w_cnt  = take(M);          // GCN edge counts (reused per graph)
  float* w_inv  = take(EUS);
  int*   rp_u   = (int*)take(N + 1);
  int*   rp_s   = (int*)take(M + 1);
  int*   cur_u  = (int*)take(N);
  int*   cur_s  = (int*)take(M);
  int*   ue_s   = (int*)take(EUS);
  float* ue_w   = take(EUS);
  int*   se_u   = (int*)take(EUS);
  float* se_w   = take(EUS);
  int*   g_rp   = (int*)take(M + 1);
  int*   g_cur  = (int*)take(M);
  int*   g_src  = (int*)take(ESmax);
  float* g_w    = take(ESmax);
  float* w_sA   = take(MD);
  float* w_sB   = take(MD);
  float* w_uA   = take(ND);
  float* w_uB   = take(ND);

  float* out = (float*)d_out;
  float* o_so1 = out;
  float* o_uo1 = o_so1 + MD;
  float* o_so2 = o_uo1 + ND;
  float* o_uo2 = o_so2 + MD;
  float* o_so3 = o_uo2 + ND;
  float* o_uo3 = o_so3 + MD;

  auto cpy = [&](float* dst, const float* src, size_t n) {
    hipMemcpyAsync(dst, src, n * sizeof(float), hipMemcpyDeviceToDevice, stream);
  };
  auto zero = [&](void* p, size_t n) { hipMemsetAsync(p, 0, n * sizeof(float), stream); };

  const int B = 256;
  auto gr = [&](size_t work) { return (int)((work + B - 1) / B); };
  const int gRows = gr(((size_t)(N + M)) * 32);   // fused prop gather
  const int gMrows = gr((size_t)M * 32);          // GCN gather

  // ---- degrees + per-edge inv_div + bipartite CSR (both directions) ----
  zero(w_udeg, N); zero(w_sdeg, M);
  k_deg<<<gr(EUS), B, 0, stream>>>(uu, ss, w_udeg, w_sdeg, EUS);
  k_invdiv<<<gr(EUS), B, 0, stream>>>(uu, ss, w_udeg, w_sdeg, w_inv, EUS);
  k_scan<<<1, 1024, 0, stream>>>(w_udeg, rp_u, N);
  k_scan<<<1, 1024, 0, stream>>>(w_sdeg, rp_s, M);
  zero(cur_u, N); zero(cur_s, M);
  k_fill_bip<<<gr(EUS), B, 0, stream>>>(uu, ss, w_inv, rp_u, rp_s, cur_u, cur_s,
                                        ue_s, ue_w, se_u, se_w, EUS);

  // ---- propagation 2 (raw embeddings); acc lives directly in so2/uo2 ----
  cpy(o_so2, spot_emb, MD); cpy(o_uo2, user_emb, ND);
  k_prop_gather<<<gRows, B, 0, stream>>>(rp_u, ue_s, ue_w, rp_s, se_u, se_w,
                                         spot_emb, user_emb, w_uB, w_sB,
                                         o_uo2, o_so2, 1.0f, N, M);
  k_prop_gather<<<gRows, B, 0, stream>>>(rp_u, ue_s, ue_w, rp_s, se_u, se_w,
                                         w_sB, w_uB, w_uA, w_sA,
                                         o_uo2, o_so2, 1.0f, N, M);
  k_prop_gather<<<gRows, B, 0, stream>>>(rp_u, ue_s, ue_w, rp_s, se_u, se_w,
                                         w_sA, w_uA, w_uB, w_sB,
                                         o_uo2, o_so2, 0.25f, N, M);
  // now o_so2/o_uo2 = p_s/p_u; w_sB = fin_s
  cpy(o_so3, o_so2, MD); cpy(o_uo3, o_uo2, ND);

  // ---- GCN branch 2: so2 += cat2/4 ----
  k_gemm<<<(M + 63) / 64, 128, 0, stream>>>(spot_emb, W2, w_sA, M);
  zero(w_dinv, M); zero(w_cnt, M);
  k_degsp<<<gr(ES2), B, 0, stream>>>(ei2 + ES2, ew2, w_dinv, ES2);
  k_dinv<<<gr(M), B, 0, stream>>>(w_dinv, M);
  k_cnt<<<gr(ES2), B, 0, stream>>>(ei2 + ES2, w_cnt, ES2);
  k_scan<<<1, 1024, 0, stream>>>(w_cnt, g_rp, M);
  zero(g_cur, M);
  k_fill_gcn<<<gr(ES2), B, 0, stream>>>(ei2, ei2 + ES2, ew2, w_dinv, g_rp, g_cur,
                                        g_src, g_w, ES2);
  k_gcn_gather<<<gMrows, B, 0, stream>>>(g_rp, g_src, g_w, w_dinv, w_sA, o_so2, 0.25f, M);

  // ---- GCN branch 3: so3 += cat3/4 (input = fin_s in w_sB) ----
  k_gemm<<<(M + 63) / 64, 128, 0, stream>>>(w_sB, W3, w_sA, M);
  zero(w_dinv, M); zero(w_cnt, M);
  k_degsp<<<gr(ES3), B, 0, stream>>>(ei3 + ES3, ew3, w_dinv, ES3);
  k_dinv<<<gr(M), B, 0, stream>>>(w_dinv, M);
  k_cnt<<<gr(ES3), B, 0, stream>>>(ei3 + ES3, w_cnt, ES3);
  k_scan<<<1, 1024, 0, stream>>>(w_cnt, g_rp, M);
  zero(g_cur, M);
  k_fill_gcn<<<gr(ES3), B, 0, stream>>>(ei3, ei3 + ES3, ew3, w_dinv, g_rp, g_cur,
                                        g_src, g_w, ES3);
  k_gcn_gather<<<gMrows, B, 0, stream>>>(g_rp, g_src, g_w, w_dinv, w_sA, o_so3, 0.25f, M);

  // ---- GCN branch 1: spot_x0 = spot_emb + cat1, then propagation 1 ----
  k_gemm<<<(M + 63) / 64, 128, 0, stream>>>(spot_emb, W1, w_sA, M);
  zero(w_dinv, M); zero(w_cnt, M);
  k_degsp<<<gr(ES1), B, 0, stream>>>(ei1 + ES1, ew1, w_dinv, ES1);
  k_dinv<<<gr(M), B, 0, stream>>>(w_dinv, M);
  k_cnt<<<gr(ES1), B, 0, stream>>>(ei1 + ES1, w_cnt, ES1);
  k_scan<<<1, 1024, 0, stream>>>(w_cnt, g_rp, M);
  zero(g_cur, M);
  k_fill_gcn<<<gr(ES1), B, 0, stream>>>(ei1, ei1 + ES1, ew1, w_dinv, g_rp, g_cur,
                                        g_src, g_w, ES1);
  cpy(w_sB, spot_emb, MD);  // spot_x0 base
  k_gcn_gather<<<gMrows, B, 0, stream>>>(g_rp, g_src, g_w, w_dinv, w_sA, w_sB, 1.0f, M);

  cpy(o_so1, w_sB, MD); cpy(o_uo1, user_emb, ND);
  k_prop_gather<<<gRows, B, 0, stream>>>(rp_u, ue_s, ue_w, rp_s, se_u, se_w,
                                         w_sB, user_emb, w_uA, w_sA,
                                         o_uo1, o_so1, 1.0f, N, M);
  k_prop_gather<<<gRows, B, 0, stream>>>(rp_u, ue_s, ue_w, rp_s, se_u, se_w,
                                         w_sA, w_uA, w_uB, w_sB,
                                         o_uo1, o_so1, 1.0f, N, M);
  k_prop_gather<<<gRows, B, 0, stream>>>(rp_u, ue_s, ue_w, rp_s, se_u, se_w,
                                         w_sB, w_uB, w_uA, w_sA,
                                         o_uo1, o_so1, 0.25f, N, M);
}

// Round 3
// 1445.020 us; speedup vs baseline: 10.8100x; 1.4124x over previous
//
#include <hip/hip_runtime.h>

#define D 128
typedef unsigned int uint;
typedef unsigned short ushort;

__device__ __forceinline__ void fadd(float* p, float v) { unsafeAtomicAdd(p, v); }

__device__ __forceinline__ float blo(uint u) { return __uint_as_float(u << 16); }
__device__ __forceinline__ float bhi(uint u) { return __uint_as_float(u & 0xffff0000u); }
__device__ __forceinline__ uint bpack(float a, float b) {
  uint ua = __float_as_uint(a), ub = __float_as_uint(b);
  ua = (ua + 0x7fffu + ((ua >> 16) & 1u)) >> 16;
  ub = (ub + 0x7fffu + ((ub >> 16) & 1u)) & 0xffff0000u;
  return ua | ub;
}

// ---- degree / norm kernels ----
__global__ void k_deg(const int* __restrict__ u, const int* __restrict__ s,
                      float* udeg, float* sdeg, int E) {
  int e = blockIdx.x * blockDim.x + threadIdx.x;
  if (e < E) {
    fadd(&udeg[u[e]], 1.0f);
    fadd(&sdeg[s[e]], 1.0f);
  }
}

__global__ void k_invdiv(const int* __restrict__ u, const int* __restrict__ s,
                         const float* __restrict__ udeg, const float* __restrict__ sdeg,
                         float* __restrict__ inv, int E) {
  int e = blockIdx.x * blockDim.x + threadIdx.x;
  if (e < E) inv[e] = rsqrtf(udeg[u[e]] * sdeg[s[e]]);
}

__global__ void k_degsp(const int* __restrict__ dst, const float* __restrict__ ew,
                        float* deg, int E) {
  int e = blockIdx.x * blockDim.x + threadIdx.x;
  if (e < E) fadd(&deg[dst[e]], ew[e]);
}

__global__ void k_dinv(float* deg, int n) {
  int i = blockIdx.x * blockDim.x + threadIdx.x;
  if (i < n) {
    float d = deg[i];
    deg[i] = d > 0.f ? rsqrtf(fmaxf(d, 1e-12f)) : 0.f;
  }
}

__global__ void k_cnt(const int* __restrict__ dst, float* cnt, int E) {
  int e = blockIdx.x * blockDim.x + threadIdx.x;
  if (e < E) fadd(&cnt[dst[e]], 1.0f);
}

// ---- exclusive prefix sum of float counts -> int row_ptr ----
__global__ __launch_bounds__(1024) void k_scan(const float* __restrict__ cnt,
                                               int* __restrict__ rp, int n) {
  __shared__ int part[1024];
  int tid = threadIdx.x;
  int chunk = (n + 1023) / 1024;
  int lo = tid * chunk;
  int hi = lo + chunk < n ? lo + chunk : n;
  if (lo > n) lo = n;
  if (hi < lo) hi = lo;
  int s = 0;
  for (int i = lo; i < hi; ++i) s += (int)cnt[i];
  part[tid] = s;
  __syncthreads();
  for (int off = 1; off < 1024; off <<= 1) {
    int v = tid >= off ? part[tid - off] : 0;
    __syncthreads();
    part[tid] += v;
    __syncthreads();
  }
  int excl = tid == 0 ? 0 : part[tid - 1];
  for (int i = lo; i < hi; ++i) {
    rp[i] = excl;
    excl += (int)cnt[i];
  }
  if (hi == n) rp[n] = excl;
}

// ---- CSR fill: bipartite (both directions at once) ----
__global__ void k_fill_bip(const int* __restrict__ u, const int* __restrict__ s,
                           const float* __restrict__ inv,
                           const int* __restrict__ rp_u, const int* __restrict__ rp_s,
                           int* cur_u, int* cur_s,
                           int* __restrict__ ue_s, float* __restrict__ ue_w,
                           int* __restrict__ se_u, float* __restrict__ se_w, int E) {
  int e = blockIdx.x * blockDim.x + threadIdx.x;
  if (e >= E) return;
  int ui = u[e], si = s[e];
  float w = inv[e];
  int p = rp_u[ui] + atomicAdd(&cur_u[ui], 1);
  ue_s[p] = si; ue_w[p] = w;
  int q = rp_s[si] + atomicAdd(&cur_s[si], 1);
  se_u[q] = ui; se_w[q] = w;
}

// ---- CSR fill: GCN graph, bucketed by dst; store ew*dinv[src] ----
__global__ void k_fill_gcn(const int* __restrict__ src, const int* __restrict__ dst,
                           const float* __restrict__ ew, const float* __restrict__ dinv,
                           const int* __restrict__ rp, int* cur,
                           int* __restrict__ esrc, float* __restrict__ ewn, int E) {
  int e = blockIdx.x * blockDim.x + threadIdx.x;
  if (e >= E) return;
  int de = dst[e];
  int p = rp[de] + atomicAdd(&cur[de], 1);
  esrc[p] = src[e];
  ewn[p] = ew[e] * dinv[src[e]];
}

// ---- f32 -> bf16 conversion (8 elems/thread) ----
__global__ void k_tobf(const float* __restrict__ src, uint* __restrict__ dst, int n8) {
  int i = blockIdx.x * blockDim.x + threadIdx.x;
  if (i < n8) {
    float4 a = ((const float4*)src)[2 * i];
    float4 b = ((const float4*)src)[2 * i + 1];
    uint4 o;
    o.x = bpack(a.x, a.y); o.y = bpack(a.z, a.w);
    o.z = bpack(b.x, b.y); o.w = bpack(b.z, b.w);
    ((uint4*)dst)[i] = o;
  }
}

// ---- fused bipartite layer: bf16 gather both directions + f32 acc update ----
__global__ void k_prop_gather(const int* __restrict__ rp_u, const int* __restrict__ ue_s,
                              const float* __restrict__ ue_w,
                              const int* __restrict__ rp_s, const int* __restrict__ se_u,
                              const float* __restrict__ se_w,
                              const ushort* __restrict__ sx, const ushort* __restrict__ ux,
                              ushort* ubf, ushort* sbf,
                              float* __restrict__ uacc, float* __restrict__ sacc,
                              float* uacc2, float* sacc2,
                              float fs, int N, int M) {
  int g = blockIdx.x * blockDim.x + threadIdx.x;
  int row = g >> 5, lane = g & 31;
  const int *rp, *ei; const float* ew; const ushort* src;
  ushort* bdst; float* acc; float* acc2; int r;
  if (row < N) {
    rp = rp_u; ei = ue_s; ew = ue_w; src = sx; bdst = ubf; acc = uacc; acc2 = uacc2; r = row;
  } else if (row < N + M) {
    rp = rp_s; ei = se_u; ew = se_w; src = ux; bdst = sbf; acc = sacc; acc2 = sacc2; r = row - N;
  } else return;
  int beg = rp[r], end = rp[r + 1];
  const uint2* sv = (const uint2*)src;  // row stride = 32 uint2 (128 bf16)
  float4 sum = make_float4(0.f, 0.f, 0.f, 0.f);
  for (int i = beg; i < end; ++i) {
    int sr = ei[i];
    float w = ew[i];
    uint2 v = sv[(size_t)sr * 32 + lane];
    sum.x = fmaf(w, blo(v.x), sum.x);
    sum.y = fmaf(w, bhi(v.x), sum.y);
    sum.z = fmaf(w, blo(v.y), sum.z);
    sum.w = fmaf(w, bhi(v.y), sum.w);
  }
  if (bdst)
    ((uint2*)bdst)[(size_t)r * 32 + lane] = make_uint2(bpack(sum.x, sum.y), bpack(sum.z, sum.w));
  float4* ap = (float4*)(acc + (size_t)r * D) + lane;
  float4 a = *ap;
  a.x = (a.x + sum.x) * fs; a.y = (a.y + sum.y) * fs;
  a.z = (a.z + sum.z) * fs; a.w = (a.w + sum.w) * fs;
  *ap = a;
  if (acc2) ((float4*)(acc2 + (size_t)r * D))[lane] = a;
}

// ---- GCN gather from bf16 xw: out[row] += scale*dinv[row]*sum(ewn*xw[src]) ----
__global__ void k_gcn_gather(const int* __restrict__ rp, const int* __restrict__ esrc,
                             const float* __restrict__ ewn, const float* __restrict__ dinv,
                             const ushort* __restrict__ xw, float* __restrict__ out,
                             float scale, int M) {
  int g = blockIdx.x * blockDim.x + threadIdx.x;
  int row = g >> 5, lane = g & 31;
  if (row >= M) return;
  int beg = rp[row], end = rp[row + 1];
  const uint2* sv = (const uint2*)xw;
  float4 sum = make_float4(0.f, 0.f, 0.f, 0.f);
  for (int i = beg; i < end; ++i) {
    int sr = esrc[i];
    float w = ewn[i];
    uint2 v = sv[(size_t)sr * 32 + lane];
    sum.x = fmaf(w, blo(v.x), sum.x);
    sum.y = fmaf(w, bhi(v.x), sum.y);
    sum.z = fmaf(w, blo(v.y), sum.z);
    sum.w = fmaf(w, bhi(v.y), sum.w);
  }
  float sc = dinv[row] * scale;
  float4* op = (float4*)(out + (size_t)row * D) + lane;
  float4 o = *op;
  o.x = fmaf(sc, sum.x, o.x); o.y = fmaf(sc, sum.y, o.y);
  o.z = fmaf(sc, sum.z, o.z); o.w = fmaf(sc, sum.w, o.w);
  *op = o;
}

// ---- GEMM: Y_bf16[rows x 128] = X[rows x 128] @ W[128 x 128] ----
// 256 threads: c=tid&31 (4-col group), rg=tid>>5 (0..7), 8 rows/thread stride 8.
__device__ __forceinline__ float4 ldx(const float* X, size_t idx) {
  return ((const float4*)X)[idx];
}
__device__ __forceinline__ float4 ldx(const ushort* X, size_t idx) {
  uint2 v = ((const uint2*)X)[idx];
  return make_float4(blo(v.x), bhi(v.x), blo(v.y), bhi(v.y));
}

template <typename XT>
__global__ __launch_bounds__(256) void k_gemm(const XT* __restrict__ X,
                                              const float* __restrict__ W,
                                              ushort* __restrict__ Y, int rows) {
  __shared__ float Wl[D * D];  // 64 KB
  int tid = threadIdx.x;
  for (int i = tid; i < D * D / 4; i += 256) ((float4*)Wl)[i] = ((const float4*)W)[i];
  __syncthreads();
  int c = tid & 31, rg = tid >> 5;
  int r0 = blockIdx.x * 64;
  float4 acc[8];
#pragma unroll
  for (int j = 0; j < 8; ++j) acc[j] = make_float4(0.f, 0.f, 0.f, 0.f);
  for (int k4 = 0; k4 < 32; ++k4) {
    float4 xv[8];
#pragma unroll
    for (int j = 0; j < 8; ++j) {
      int r = r0 + rg + 8 * j;
      if (r >= rows) r = rows - 1;  // clamped load, store is guarded
      xv[j] = ldx(X, (size_t)r * 32 + k4);
    }
#pragma unroll
    for (int kk = 0; kk < 4; ++kk) {
      float4 wv = ((float4*)Wl)[(k4 * 4 + kk) * 32 + c];
#pragma unroll
      for (int j = 0; j < 8; ++j) {
        float xs = kk == 0 ? xv[j].x : kk == 1 ? xv[j].y : kk == 2 ? xv[j].z : xv[j].w;
        acc[j].x = fmaf(xs, wv.x, acc[j].x);
        acc[j].y = fmaf(xs, wv.y, acc[j].y);
        acc[j].z = fmaf(xs, wv.z, acc[j].z);
        acc[j].w = fmaf(xs, wv.w, acc[j].w);
      }
    }
  }
#pragma unroll
  for (int j = 0; j < 8; ++j) {
    int r = r0 + rg + 8 * j;
    if (r < rows)
      ((uint2*)(Y + (size_t)r * D))[c] =
          make_uint2(bpack(acc[j].x, acc[j].y), bpack(acc[j].z, acc[j].w));
  }
}

extern "C" void kernel_launch(void* const* d_in, const int* in_sizes, int n_in,
                              void* d_out, int out_size, void* d_ws, size_t ws_size,
                              hipStream_t stream) {
  const float* spot_emb = (const float*)d_in[0];
  const float* user_emb = (const float*)d_in[1];
  const float* W1 = (const float*)d_in[2];
  const float* W2 = (const float*)d_in[3];
  const float* W3 = (const float*)d_in[4];
  const float* ew1 = (const float*)d_in[5];
  const float* ew2 = (const float*)d_in[6];
  const float* ew3 = (const float*)d_in[7];
  const int* us = (const int*)d_in[8];
  const int* ei1 = (const int*)d_in[9];
  const int* ei2 = (const int*)d_in[10];
  const int* ei3 = (const int*)d_in[11];

  const int M = in_sizes[0] / D;
  const int N = in_sizes[1] / D;
  const int EUS = in_sizes[8] / 2;
  const int ES1 = in_sizes[9] / 2;
  const int ES2 = in_sizes[10] / 2;
  const int ES3 = in_sizes[11] / 2;
  const int ESmax = ES1 > ES2 ? (ES1 > ES3 ? ES1 : ES3) : (ES2 > ES3 ? ES2 : ES3);

  const int* uu = us;        // user index per edge
  const int* ss = us + EUS;  // spot index per edge

  const size_t MD = (size_t)M * D, ND = (size_t)N * D;
  auto al = [](size_t x) { return (x + 63) & ~(size_t)63; };
  float* ws = (float*)d_ws;
  auto take = [&](size_t n) { float* p = ws; ws += al(n); return p; };

  float* w_udeg = take(N);
  float* w_sdeg = take(M);
  float* w_dinv = take(M);
  float* w_cnt  = take(M);
  float* w_inv  = take(EUS);
  int*   rp_u   = (int*)take(N + 1);
  int*   rp_s   = (int*)take(M + 1);
  int*   cur_u  = (int*)take(N);
  int*   cur_s  = (int*)take(M);
  int*   ue_s   = (int*)take(EUS);
  float* ue_w   = take(EUS);
  int*   se_u   = (int*)take(EUS);
  float* se_w   = take(EUS);
  int*   g_rp   = (int*)take(M + 1);
  int*   g_cur  = (int*)take(M);
  int*   g_src  = (int*)take(ESmax);
  float* g_w    = take(ESmax);
  ushort* xw_bf = (ushort*)take(MD / 2);
  ushort* sp_bf = (ushort*)take(MD / 2);
  ushort* sA_bf = (ushort*)take(MD / 2);
  ushort* sB_bf = (ushort*)take(MD / 2);
  ushort* us_bf = (ushort*)take(ND / 2);
  ushort* uA_bf = (ushort*)take(ND / 2);
  ushort* uB_bf = (ushort*)take(ND / 2);

  float* out = (float*)d_out;
  float* o_so1 = out;
  float* o_uo1 = o_so1 + MD;
  float* o_so2 = o_uo1 + ND;
  float* o_uo2 = o_so2 + MD;
  float* o_so3 = o_uo2 + ND;
  float* o_uo3 = o_so3 + MD;

  auto cpy = [&](float* dst, const float* src, size_t n) {
    hipMemcpyAsync(dst, src, n * sizeof(float), hipMemcpyDeviceToDevice, stream);
  };
  auto zero = [&](void* p, size_t n) { hipMemsetAsync(p, 0, n * sizeof(float), stream); };

  const int B = 256;
  auto gr = [&](size_t work) { return (int)((work + B - 1) / B); };
  const int gRows = gr(((size_t)(N + M)) * 32);
  const int gMrows = gr((size_t)M * 32);
  const int gGemm = (M + 63) / 64;
  ushort* nul = (ushort*)nullptr;
  float* nulf = (float*)nullptr;

  // ---- degrees + inv_div + bipartite CSR ----
  zero(w_udeg, N); zero(w_sdeg, M);
  k_deg<<<gr(EUS), B, 0, stream>>>(uu, ss, w_udeg, w_sdeg, EUS);
  k_invdiv<<<gr(EUS), B, 0, stream>>>(uu, ss, w_udeg, w_sdeg, w_inv, EUS);
  k_scan<<<1, 1024, 0, stream>>>(w_udeg, rp_u, N);
  k_scan<<<1, 1024, 0, stream>>>(w_sdeg, rp_s, M);
  zero(cur_u, N); zero(cur_s, M);
  k_fill_bip<<<gr(EUS), B, 0, stream>>>(uu, ss, w_inv, rp_u, rp_s, cur_u, cur_s,
                                        ue_s, ue_w, se_u, se_w, EUS);

  // bf16 copies of the raw embeddings
  k_tobf<<<gr(MD / 8), B, 0, stream>>>(spot_emb, (uint*)sp_bf, (int)(MD / 8));
  k_tobf<<<gr(ND / 8), B, 0, stream>>>(user_emb, (uint*)us_bf, (int)(ND / 8));

  // ---- propagation 2 (raw embeddings); acc in so2/uo2; p also -> so3/uo3 ----
  cpy(o_so2, spot_emb, MD); cpy(o_uo2, user_emb, ND);
  k_prop_gather<<<gRows, B, 0, stream>>>(rp_u, ue_s, ue_w, rp_s, se_u, se_w,
                                         sp_bf, us_bf, uB_bf, sB_bf,
                                         o_uo2, o_so2, nulf, nulf, 1.0f, N, M);
  k_prop_gather<<<gRows, B, 0, stream>>>(rp_u, ue_s, ue_w, rp_s, se_u, se_w,
                                         sB_bf, uB_bf, uA_bf, sA_bf,
                                         o_uo2, o_so2, nulf, nulf, 1.0f, N, M);
  k_prop_gather<<<gRows, B, 0, stream>>>(rp_u, ue_s, ue_w, rp_s, se_u, se_w,
                                         sA_bf, uA_bf, nul, sB_bf,   // sB_bf = fin_s (bf16)
                                         o_uo2, o_so2, o_uo3, o_so3, 0.25f, N, M);

  // ---- GCN branch 2: so2 += cat2/4 ----
  k_gemm<float><<<gGemm, 256, 0, stream>>>(spot_emb, W2, xw_bf, M);
  zero(w_dinv, M); zero(w_cnt, M);
  k_degsp<<<gr(ES2), B, 0, stream>>>(ei2 + ES2, ew2, w_dinv, ES2);
  k_dinv<<<gr(M), B, 0, stream>>>(w_dinv, M);
  k_cnt<<<gr(ES2), B, 0, stream>>>(ei2 + ES2, w_cnt, ES2);
  k_scan<<<1, 1024, 0, stream>>>(w_cnt, g_rp, M);
  zero(g_cur, M);
  k_fill_gcn<<<gr(ES2), B, 0, stream>>>(ei2, ei2 + ES2, ew2, w_dinv, g_rp, g_cur,
                                        g_src, g_w, ES2);
  k_gcn_gather<<<gMrows, B, 0, stream>>>(g_rp, g_src, g_w, w_dinv, xw_bf, o_so2, 0.25f, M);

  // ---- GCN branch 3: so3 += cat3/4 (input = fin_s bf16 in sB_bf) ----
  k_gemm<ushort><<<gGemm, 256, 0, stream>>>((const ushort*)sB_bf, W3, xw_bf, M);
  zero(w_dinv, M); zero(w_cnt, M);
  k_degsp<<<gr(ES3), B, 0, stream>>>(ei3 + ES3, ew3, w_dinv, ES3);
  k_dinv<<<gr(M), B, 0, stream>>>(w_dinv, M);
  k_cnt<<<gr(ES3), B, 0, stream>>>(ei3 + ES3, w_cnt, ES3);
  k_scan<<<1, 1024, 0, stream>>>(w_cnt, g_rp, M);
  zero(g_cur, M);
  k_fill_gcn<<<gr(ES3), B, 0, stream>>>(ei3, ei3 + ES3, ew3, w_dinv, g_rp, g_cur,
                                        g_src, g_w, ES3);
  k_gcn_gather<<<gMrows, B, 0, stream>>>(g_rp, g_src, g_w, w_dinv, xw_bf, o_so3, 0.25f, M);

  // ---- GCN branch 1: spot_x0 = spot_emb + cat1 (built in o_so1), then prop 1 ----
  k_gemm<float><<<gGemm, 256, 0, stream>>>(spot_emb, W1, xw_bf, M);
  zero(w_dinv, M); zero(w_cnt, M);
  k_degsp<<<gr(ES1), B, 0, stream>>>(ei1 + ES1, ew1, w_dinv, ES1);
  k_dinv<<<gr(M), B, 0, stream>>>(w_dinv, M);
  k_cnt<<<gr(ES1), B, 0, stream>>>(ei1 + ES1, w_cnt, ES1);
  k_scan<<<1, 1024, 0, stream>>>(w_cnt, g_rp, M);
  zero(g_cur, M);
  k_fill_gcn<<<gr(ES1), B, 0, stream>>>(ei1, ei1 + ES1, ew1, w_dinv, g_rp, g_cur,
                                        g_src, g_w, ES1);
  cpy(o_so1, spot_emb, MD);
  k_gcn_gather<<<gMrows, B, 0, stream>>>(g_rp, g_src, g_w, w_dinv, xw_bf, o_so1, 1.0f, M);
  k_tobf<<<gr(MD / 8), B, 0, stream>>>(o_so1, (uint*)sp_bf, (int)(MD / 8));
  cpy(o_uo1, user_emb, ND);

  k_prop_gather<<<gRows, B, 0, stream>>>(rp_u, ue_s, ue_w, rp_s, se_u, se_w,
                                         sp_bf, us_bf, uB_bf, sB_bf,
                                         o_uo1, o_so1, nulf, nulf, 1.0f, N, M);
  k_prop_gather<<<gRows, B, 0, stream>>>(rp_u, ue_s, ue_w, rp_s, se_u, se_w,
                                         sB_bf, uB_bf, uA_bf, sA_bf,
                                         o_uo1, o_so1, nulf, nulf, 1.0f, N, M);
  k_prop_gather<<<gRows, B, 0, stream>>>(rp_u, ue_s, ue_w, rp_s, se_u, se_w,
                                         sA_bf, uA_bf, nul, nul,
                                         o_uo1, o_so1, nulf, nulf, 0.25f, N, M);
}

// Round 4
// 986.071 us; speedup vs baseline: 15.8413x; 1.4654x over previous
//
#include <hip/hip_runtime.h>
#include <hip/hip_fp16.h>

#define D 128
typedef unsigned int uint;
typedef unsigned short ushort;

__device__ __forceinline__ void fadd(float* p, float v) { unsafeAtomicAdd(p, v); }

__device__ __forceinline__ float blo(uint u) { return __uint_as_float(u << 16); }
__device__ __forceinline__ float bhi(uint u) { return __uint_as_float(u & 0xffff0000u); }
__device__ __forceinline__ uint bpack(float a, float b) {
  uint ua = __float_as_uint(a), ub = __float_as_uint(b);
  ua = (ua + 0x7fffu + ((ua >> 16) & 1u)) >> 16;
  ub = (ub + 0x7fffu + ((ub >> 16) & 1u)) & 0xffff0000u;
  return ua | ub;
}
__device__ __forceinline__ float h2f(ushort h) { return __half2float(__ushort_as_half(h)); }
__device__ __forceinline__ ushort f2h(float f) { return __half_as_ushort(__float2half(f)); }

// ---- bipartite degree counts (also become dinv tables in-place) ----
__global__ void k_deg(const int* __restrict__ u, const int* __restrict__ s,
                      float* udeg, float* sdeg, int E) {
  int e = blockIdx.x * blockDim.x + threadIdx.x;
  if (e < E) {
    fadd(&udeg[u[e]], 1.0f);
    fadd(&sdeg[s[e]], 1.0f);
  }
}

// ---- all 3 GCN graphs: weighted degree + edge count in one pass ----
__global__ void k_degcnt3(const int* __restrict__ ei1, const int* __restrict__ ei2,
                          const int* __restrict__ ei3, const float* __restrict__ ew1,
                          const float* __restrict__ ew2, const float* __restrict__ ew3,
                          int ES1, int ES2, int ES3, float* gdeg, float* gcnt, int AM,
                          int EStot) {
  int e = blockIdx.x * blockDim.x + threadIdx.x;
  if (e >= EStot) return;
  const int* ei; const float* ew; int g, le, ESg;
  if (e < ES1) { g = 0; le = e; ei = ei1; ew = ew1; ESg = ES1; }
  else if (e < ES1 + ES2) { g = 1; le = e - ES1; ei = ei2; ew = ew2; ESg = ES2; }
  else { g = 2; le = e - ES1 - ES2; ei = ei3; ew = ew3; ESg = ES3; }
  int dst = ei[ESg + le];
  fadd(&gdeg[g * AM + dst], ew[le]);
  fadd(&gcnt[g * AM + dst], 1.0f);
}

// ---- 5-segment exclusive scan (u, s, 3 GCN graphs) in one dispatch ----
__device__ void scan_body(const float* __restrict__ cnt, int* __restrict__ rp, int n) {
  __shared__ int part[1024];
  int tid = threadIdx.x;
  int chunk = (n + 1023) / 1024;
  int lo = tid * chunk;
  int hi = lo + chunk < n ? lo + chunk : n;
  if (lo > n) lo = n;
  if (hi < lo) hi = lo;
  int s = 0;
  for (int i = lo; i < hi; ++i) s += (int)cnt[i];
  part[tid] = s;
  __syncthreads();
  for (int off = 1; off < 1024; off <<= 1) {
    int v = tid >= off ? part[tid - off] : 0;
    __syncthreads();
    part[tid] += v;
    __syncthreads();
  }
  int excl = tid == 0 ? 0 : part[tid - 1];
  for (int i = lo; i < hi; ++i) {
    rp[i] = excl;
    excl += (int)cnt[i];
  }
  if (hi == n) rp[n] = excl;
}

__global__ __launch_bounds__(1024) void k_scan5(const float* udeg, const float* sdeg,
                                                const float* gcnt, int AM, int* rp_u,
                                                int* rp_s, int* grp, int N, int M) {
  int b = blockIdx.x;
  if (b == 0) scan_body(udeg, rp_u, N);
  else if (b == 1) scan_body(sdeg, rp_s, M);
  else scan_body(gcnt + (size_t)(b - 2) * AM, grp + (size_t)(b - 2) * (M + 1), M);
}

// ---- all dinv tables in place ----
__global__ void k_dinv_all(float* udeg, float* sdeg, float* gdeg, int N, int M, int AM) {
  int i = blockIdx.x * blockDim.x + threadIdx.x;
  if (i < N) {
    float d = udeg[i]; udeg[i] = d > 0.f ? rsqrtf(d) : 0.f;
  } else if (i < N + M) {
    int j = i - N; float d = sdeg[j]; sdeg[j] = d > 0.f ? rsqrtf(d) : 0.f;
  } else {
    int j = i - N - M;
    if (j >= 3 * M) return;
    int g = j / M, k = j % M;
    float d = gdeg[g * AM + k];
    gdeg[g * AM + k] = d > 0.f ? rsqrtf(fmaxf(d, 1e-12f)) : 0.f;
  }
}

// ---- bipartite CSR fill: index-only (ushort) ----
__global__ void k_fill_bip(const int* __restrict__ uu, const int* __restrict__ ss,
                           const int* __restrict__ rp_u, const int* __restrict__ rp_s,
                           int* cur_u, int* cur_s, ushort* __restrict__ ue_s,
                           ushort* __restrict__ se_u, int E) {
  int e = blockIdx.x * blockDim.x + threadIdx.x;
  if (e >= E) return;
  int ui = uu[e], si = ss[e];
  int p = rp_u[ui] + atomicAdd(&cur_u[ui], 1);
  ue_s[p] = (ushort)si;
  int q = rp_s[si] + atomicAdd(&cur_s[si], 1);
  se_u[q] = (ushort)ui;
}

// ---- GCN CSR fill (all 3 graphs): packed uint {src:16 | half(ew*dinv[src]):16} ----
__global__ void k_fill_gcn3(const int* __restrict__ ei1, const int* __restrict__ ei2,
                            const int* __restrict__ ei3, const float* __restrict__ ew1,
                            const float* __restrict__ ew2, const float* __restrict__ ew3,
                            int ES1, int ES2, int ES3, const float* __restrict__ gdinv,
                            const int* __restrict__ grp, int* gcur, uint* __restrict__ gsrc,
                            int M, int AM, int EStot) {
  int e = blockIdx.x * blockDim.x + threadIdx.x;
  if (e >= EStot) return;
  const int* ei; const float* ew; int g, le, ESg, goff;
  if (e < ES1) { g = 0; le = e; ei = ei1; ew = ew1; ESg = ES1; goff = 0; }
  else if (e < ES1 + ES2) { g = 1; le = e - ES1; ei = ei2; ew = ew2; ESg = ES2; goff = ES1; }
  else { g = 2; le = e - ES1 - ES2; ei = ei3; ew = ew3; ESg = ES3; goff = ES1 + ES2; }
  int src = ei[le], dst = ei[ESg + le];
  float w = ew[le] * gdinv[g * AM + src];
  int p = grp[(size_t)g * (M + 1) + dst] + atomicAdd(&gcur[g * AM + dst], 1);
  gsrc[goff + p] = (uint)src | ((uint)f2h(w) << 16);
}

// ---- pack f32 emb into dual-signal bf16 tables (sig1 = sig2 = emb) ----
__global__ void k_pack_dual(const float* __restrict__ ue, const float* __restrict__ se,
                            uint4* __restrict__ UC, uint4* __restrict__ SC, int N, int M) {
  int g = blockIdx.x * blockDim.x + threadIdx.x;
  int row = g >> 5, lane = g & 31;
  const float* src; uint4* dst; int r;
  if (row < N) { src = ue; dst = UC; r = row; }
  else if (row < N + M) { src = se; dst = SC; r = row - N; }
  else return;
  float4 v = ((const float4*)src)[(size_t)r * 32 + lane];
  uint a = bpack(v.x, v.y), b = bpack(v.z, v.w);
  dst[(size_t)r * 32 + lane] = make_uint4(a, b, a, b);
}

// ---- fused dual-signal bipartite layer ----
__global__ void k_prop_dual(
    const int* __restrict__ rp_u, const ushort* __restrict__ ue_s,
    const int* __restrict__ rp_s, const ushort* __restrict__ se_u,
    const float* __restrict__ dinv_u, const float* __restrict__ dinv_s,
    const uint4* __restrict__ SCin, const uint4* __restrict__ UCin,
    uint4* __restrict__ SCout, uint4* __restrict__ UCout,
    const float* __restrict__ base_u1, const float* __restrict__ base_u2,
    const float* __restrict__ base_s1, const float* __restrict__ base_s2,
    float* __restrict__ acc_u1, float* __restrict__ acc_u2,
    float* __restrict__ acc_s1, float* __restrict__ acc_s2,
    float* dup_u2, float* dup_s2, float fs, int N, int M) {
  int g = blockIdx.x * blockDim.x + threadIdx.x;
  int row = g >> 5, lane = g & 31;
  const int* rp; const ushort* ei; const float* dopp; const uint4* tbl;
  uint4* otbl; const float *b1, *b2; float *a1, *a2, *d2; float wrow; int r;
  if (row < N) {
    r = row; rp = rp_u; ei = ue_s; dopp = dinv_s; tbl = SCin; otbl = UCout;
    b1 = base_u1; b2 = base_u2; a1 = acc_u1; a2 = acc_u2; d2 = dup_u2;
    wrow = dinv_u[r];
  } else if (row < N + M) {
    r = row - N; rp = rp_s; ei = se_u; dopp = dinv_u; tbl = UCin; otbl = SCout;
    b1 = base_s1; b2 = base_s2; a1 = acc_s1; a2 = acc_s2; d2 = dup_s2;
    wrow = dinv_s[r];
  } else return;
  int beg = rp[r], end = rp[r + 1];
  float4 s1 = make_float4(0.f, 0.f, 0.f, 0.f), s2 = s1;
  for (int i = beg; i < end; ++i) {
    int idx = ei[i];
    float w = wrow * dopp[idx];
    uint4 v = tbl[(size_t)idx * 32 + lane];
    s1.x = fmaf(w, blo(v.x), s1.x); s1.y = fmaf(w, bhi(v.x), s1.y);
    s1.z = fmaf(w, blo(v.y), s1.z); s1.w = fmaf(w, bhi(v.y), s1.w);
    s2.x = fmaf(w, blo(v.z), s2.x); s2.y = fmaf(w, bhi(v.z), s2.y);
    s2.z = fmaf(w, blo(v.w), s2.z); s2.w = fmaf(w, bhi(v.w), s2.w);
  }
  size_t li = (size_t)r * 32 + lane;
  if (otbl)
    otbl[li] = make_uint4(bpack(s1.x, s1.y), bpack(s1.z, s1.w),
                          bpack(s2.x, s2.y), bpack(s2.z, s2.w));
  float4 vb1 = ((const float4*)b1)[li];
  float4 o1 = make_float4((vb1.x + s1.x) * fs, (vb1.y + s1.y) * fs,
                          (vb1.z + s1.z) * fs, (vb1.w + s1.w) * fs);
  ((float4*)a1)[li] = o1;
  float4 vb2 = ((const float4*)b2)[li];
  float4 o2 = make_float4((vb2.x + s2.x) * fs, (vb2.y + s2.y) * fs,
                          (vb2.z + s2.z) * fs, (vb2.w + s2.w) * fs);
  ((float4*)a2)[li] = o2;
  if (d2) ((float4*)d2)[li] = o2;
}

// ---- GCN gather from packed edge recs: out = base + scale*dinv[row]*sum ----
__global__ void k_gcn_gather(const int* __restrict__ rp, const uint* __restrict__ erec,
                             const float* __restrict__ dinv, const ushort* __restrict__ xw,
                             const float* __restrict__ base, float* __restrict__ out,
                             uint2* outSC, float scale, int M) {
  int g = blockIdx.x * blockDim.x + threadIdx.x;
  int row = g >> 5, lane = g & 31;
  if (row >= M) return;
  int beg = rp[row], end = rp[row + 1];
  const uint2* sv = (const uint2*)xw;
  float4 sum = make_float4(0.f, 0.f, 0.f, 0.f);
  for (int i = beg; i < end; ++i) {
    uint rec = erec[i];
    int sr = rec & 0xffffu;
    float w = h2f((ushort)(rec >> 16));
    uint2 v = sv[(size_t)sr * 32 + lane];
    sum.x = fmaf(w, blo(v.x), sum.x); sum.y = fmaf(w, bhi(v.x), sum.y);
    sum.z = fmaf(w, blo(v.y), sum.z); sum.w = fmaf(w, bhi(v.y), sum.w);
  }
  float sc = dinv[row] * scale;
  size_t li = (size_t)row * 32 + lane;
  float4 b = ((const float4*)base)[li];
  float4 o = make_float4(fmaf(sc, sum.x, b.x), fmaf(sc, sum.y, b.y),
                         fmaf(sc, sum.z, b.z), fmaf(sc, sum.w, b.w));
  ((float4*)out)[li] = o;
  if (outSC) outSC[li * 2] = make_uint2(bpack(o.x, o.y), bpack(o.z, o.w));
}

// ---- GEMM: Y_bf16[rows x 128] = X[rows x 128] @ W[128 x 128] ----
struct DualHi { const uint4* p; };
__device__ __forceinline__ float4 ldx(const float* X, size_t i) {
  return ((const float4*)X)[i];
}
__device__ __forceinline__ float4 ldx(DualHi X, size_t i) {
  uint4 v = X.p[i];
  return make_float4(blo(v.z), bhi(v.z), blo(v.w), bhi(v.w));
}

template <typename XT>
__global__ __launch_bounds__(256) void k_gemm(XT X, const float* __restrict__ W,
                                              ushort* __restrict__ Y, int rows) {
  __shared__ float Wl[D * D];
  int tid = threadIdx.x;
  for (int i = tid; i < D * D / 4; i += 256) ((float4*)Wl)[i] = ((const float4*)W)[i];
  __syncthreads();
  int c = tid & 31, rg = tid >> 5;
  int r0 = blockIdx.x * 64;
  float4 acc[8];
#pragma unroll
  for (int j = 0; j < 8; ++j) acc[j] = make_float4(0.f, 0.f, 0.f, 0.f);
  for (int k4 = 0; k4 < 32; ++k4) {
    float4 xv[8];
#pragma unroll
    for (int j = 0; j < 8; ++j) {
      int r = r0 + rg + 8 * j;
      if (r >= rows) r = rows - 1;
      xv[j] = ldx(X, (size_t)r * 32 + k4);
    }
#pragma unroll
    for (int kk = 0; kk < 4; ++kk) {
      float4 wv = ((float4*)Wl)[(k4 * 4 + kk) * 32 + c];
#pragma unroll
      for (int j = 0; j < 8; ++j) {
        float xs = kk == 0 ? xv[j].x : kk == 1 ? xv[j].y : kk == 2 ? xv[j].z : xv[j].w;
        acc[j].x = fmaf(xs, wv.x, acc[j].x);
        acc[j].y = fmaf(xs, wv.y, acc[j].y);
        acc[j].z = fmaf(xs, wv.z, acc[j].z);
        acc[j].w = fmaf(xs, wv.w, acc[j].w);
      }
    }
  }
#pragma unroll
  for (int j = 0; j < 8; ++j) {
    int r = r0 + rg + 8 * j;
    if (r < rows)
      ((uint2*)(Y + (size_t)r * D))[c] =
          make_uint2(bpack(acc[j].x, acc[j].y), bpack(acc[j].z, acc[j].w));
  }
}

extern "C" void kernel_launch(void* const* d_in, const int* in_sizes, int n_in,
                              void* d_out, int out_size, void* d_ws, size_t ws_size,
                              hipStream_t stream) {
  const float* spot_emb = (const float*)d_in[0];
  const float* user_emb = (const float*)d_in[1];
  const float* W1 = (const float*)d_in[2];
  const float* W2 = (const float*)d_in[3];
  const float* W3 = (const float*)d_in[4];
  const float* ew1 = (const float*)d_in[5];
  const float* ew2 = (const float*)d_in[6];
  const float* ew3 = (const float*)d_in[7];
  const int* us = (const int*)d_in[8];
  const int* ei1 = (const int*)d_in[9];
  const int* ei2 = (const int*)d_in[10];
  const int* ei3 = (const int*)d_in[11];

  const int M = in_sizes[0] / D;
  const int N = in_sizes[1] / D;
  const int EUS = in_sizes[8] / 2;
  const int ES1 = in_sizes[9] / 2;
  const int ES2 = in_sizes[10] / 2;
  const int ES3 = in_sizes[11] / 2;
  const int EStot = ES1 + ES2 + ES3;

  const int* uu = us;
  const int* ss = us + EUS;

  const size_t MD = (size_t)M * D, ND = (size_t)N * D;
  const int AM = (int)((M + 63) & ~63);

  float* cur = (float*)d_ws;
  auto take = [&](size_t n) { float* p = cur; cur += (n + 63) & ~(size_t)63; return p; };

  // zero-group A: degree/count accumulators
  float* udeg = take(N);
  float* sdeg = take(M);
  float* gdeg = take((size_t)3 * AM);
  float* gcnt = take((size_t)3 * AM);
  float* zeroA_end = cur;
  // zero-group B: fill cursors
  int* cur_u = (int*)take(N);
  int* cur_s = (int*)take(M);
  int* gcur = (int*)take((size_t)3 * AM);
  float* zeroB_end = cur;
  int* rp_u = (int*)take(N + 1);
  int* rp_s = (int*)take(M + 1);
  int* grp = (int*)take((size_t)3 * (M + 1));
  ushort* ue_s = (ushort*)take(EUS / 2 + 32);
  ushort* se_u = (ushort*)take(EUS / 2 + 32);
  uint* gsrc = (uint*)take(EStot);
  ushort* xw = (ushort*)take(MD / 2);
  uint4* UC_A = (uint4*)take(ND);
  uint4* UC_B = (uint4*)take(ND);
  uint4* SC_A = (uint4*)take(MD);
  uint4* SC_B = (uint4*)take(MD);

  float* out = (float*)d_out;
  float* o_so1 = out;
  float* o_uo1 = o_so1 + MD;
  float* o_so2 = o_uo1 + ND;
  float* o_uo2 = o_so2 + MD;
  float* o_so3 = o_uo2 + ND;
  float* o_uo3 = o_so3 + MD;

  const int B = 256;
  auto gr = [&](size_t work) { return (int)((work + B - 1) / B); };
  const int gProp = gr((size_t)(N + M) * 32);
  const int gM32 = gr((size_t)M * 32);
  const int gGemm = (M + 63) / 64;
  float* nulf = (float*)nullptr;

  hipMemsetAsync(udeg, 0, (char*)zeroA_end - (char*)udeg, stream);
  hipMemsetAsync(cur_u, 0, (char*)zeroB_end - (char*)cur_u, stream);

  // degrees & counts
  k_deg<<<gr(EUS), B, 0, stream>>>(uu, ss, udeg, sdeg, EUS);
  k_degcnt3<<<gr(EStot), B, 0, stream>>>(ei1, ei2, ei3, ew1, ew2, ew3,
                                         ES1, ES2, ES3, gdeg, gcnt, AM, EStot);
  // row pointers (5 segments, one dispatch)
  k_scan5<<<5, 1024, 0, stream>>>(udeg, sdeg, gcnt, AM, rp_u, rp_s, grp, N, M);
  // dinv tables in place
  k_dinv_all<<<gr((size_t)N + 4 * (size_t)M), B, 0, stream>>>(udeg, sdeg, gdeg, N, M, AM);
  // CSR fills
  k_fill_bip<<<gr(EUS), B, 0, stream>>>(uu, ss, rp_u, rp_s, cur_u, cur_s, ue_s, se_u, EUS);
  k_fill_gcn3<<<gr(EStot), B, 0, stream>>>(ei1, ei2, ei3, ew1, ew2, ew3, ES1, ES2, ES3,
                                           gdeg, grp, gcur, gsrc, M, AM, EStot);
  // dual-signal bf16 tables (sig1 = sig2 = raw emb; gg1 overwrites spot sig1)
  k_pack_dual<<<gProp, B, 0, stream>>>(user_emb, spot_emb, UC_A, SC_A, N, M);

  // branch-1 conv: o_so1 = spot_emb + cat1 (f32 + SC_A sig1 bf16)
  k_gemm<<<gGemm, 256, 0, stream>>>(spot_emb, W1, xw, M);
  k_gcn_gather<<<gM32, B, 0, stream>>>(grp, gsrc, gdeg, xw, spot_emb, o_so1,
                                       (uint2*)SC_A, 1.0f, M);

  // fused propagation: 3 layers, both signals
  k_prop_dual<<<gProp, B, 0, stream>>>(rp_u, ue_s, rp_s, se_u, udeg, sdeg,
                                       SC_A, UC_A, SC_B, UC_B,
                                       user_emb, user_emb, o_so1, spot_emb,
                                       o_uo1, o_uo2, o_so1, o_so2,
                                       nulf, nulf, 1.0f, N, M);
  k_prop_dual<<<gProp, B, 0, stream>>>(rp_u, ue_s, rp_s, se_u, udeg, sdeg,
                                       SC_B, UC_B, SC_A, UC_A,
                                       o_uo1, o_uo2, o_so1, o_so2,
                                       o_uo1, o_uo2, o_so1, o_so2,
                                       nulf, nulf, 1.0f, N, M);
  k_prop_dual<<<gProp, B, 0, stream>>>(rp_u, ue_s, rp_s, se_u, udeg, sdeg,
                                       SC_A, UC_A, SC_B, (uint4*)nullptr,
                                       o_uo1, o_uo2, o_so1, o_so2,
                                       o_uo1, o_uo2, o_so1, o_so2,
                                       o_uo3, o_so3, 0.25f, N, M);

  // branch 2: so2 += cat2/4
  k_gemm<<<gGemm, 256, 0, stream>>>(spot_emb, W2, xw, M);
  k_gcn_gather<<<gM32, B, 0, stream>>>(grp + (M + 1), gsrc + ES1, gdeg + AM, xw,
                                       o_so2, o_so2, (uint2*)nullptr, 0.25f, M);

  // branch 3: so3 += cat3/4 (input fin_s = SC_B sig2)
  k_gemm<<<gGemm, 256, 0, stream>>>(DualHi{SC_B}, W3, xw, M);
  k_gcn_gather<<<gM32, B, 0, stream>>>(grp + 2 * (M + 1), gsrc + ES1 + ES2,
                                       gdeg + 2 * AM, xw, o_so3, o_so3,
                                       (uint2*)nullptr, 0.25f, M);
}

// Round 5
// 918.008 us; speedup vs baseline: 17.0158x; 1.0741x over previous
//
#include <hip/hip_runtime.h>
#include <hip/hip_fp16.h>

#define D 128
typedef unsigned int uint;
typedef unsigned short ushort;
typedef unsigned long long ull;

__device__ __forceinline__ void fadd(float* p, float v) { unsafeAtomicAdd(p, v); }

__device__ __forceinline__ float blo(uint u) { return __uint_as_float(u << 16); }
__device__ __forceinline__ float bhi(uint u) { return __uint_as_float(u & 0xffff0000u); }
__device__ __forceinline__ uint bpack(float a, float b) {
  uint ua = __float_as_uint(a), ub = __float_as_uint(b);
  ua = (ua + 0x7fffu + ((ua >> 16) & 1u)) >> 16;
  ub = (ub + 0x7fffu + ((ub >> 16) & 1u)) & 0xffff0000u;
  return ua | ub;
}
__device__ __forceinline__ float h2f(ushort h) { return __half2float(__ushort_as_half(h)); }
__device__ __forceinline__ ushort f2h(float f) { return __half_as_ushort(__float2half(f)); }

#define PKSCALE 16777216.0f
#define PKMASK ((1ULL << 40) - 1)

// ---- all degrees in one pass: bipartite f32 counts + GCN packed (wdeg|cnt) ----
__global__ void k_alldeg(const int* __restrict__ uu, const int* __restrict__ ss, int EUS,
                         const int* __restrict__ ei1, const int* __restrict__ ei2,
                         const int* __restrict__ ei3, const float* __restrict__ ew1,
                         const float* __restrict__ ew2, const float* __restrict__ ew3,
                         int ES1, int ES2, int ES3, float* udeg, float* sdeg,
                         ull* gpk, int AM, int Etot) {
  int e = blockIdx.x * blockDim.x + threadIdx.x;
  if (e >= Etot) return;
  if (e < EUS) {
    fadd(&udeg[uu[e]], 1.0f);
    fadd(&sdeg[ss[e]], 1.0f);
  } else {
    int t = e - EUS;
    const int* ei; const float* ew; int g, le, ESg;
    if (t < ES1) { g = 0; le = t; ei = ei1; ew = ew1; ESg = ES1; }
    else if (t < ES1 + ES2) { g = 1; le = t - ES1; ei = ei2; ew = ew2; ESg = ES2; }
    else { g = 2; le = t - ES1 - ES2; ei = ei3; ew = ew3; ESg = ES3; }
    int dst = ei[ESg + le];
    ull pk = (1ULL << 40) | (ull)(uint)(ew[le] * PKSCALE);
    atomicAdd(&gpk[(size_t)g * AM + dst], pk);
  }
}

// ---- 5-segment scan + all dinv transforms, one dispatch ----
__device__ void scan_core(int my, int* __restrict__ rp, int lo, int hi, int n,
                          const float* fc, const ull* pc) {
  __shared__ int part[1024];
  int tid = threadIdx.x;
  part[tid] = my;
  __syncthreads();
  for (int off = 1; off < 1024; off <<= 1) {
    int v = tid >= off ? part[tid - off] : 0;
    __syncthreads();
    part[tid] += v;
    __syncthreads();
  }
  int excl = tid == 0 ? 0 : part[tid - 1];
  for (int i = lo; i < hi; ++i) {
    rp[i] = excl;
    excl += fc ? (int)fc[i] : (int)(pc[i] >> 40);
  }
  if (hi == n) rp[n] = excl;
}

__global__ __launch_bounds__(1024) void k_scan5(float* udeg, float* sdeg,
                                                const ull* gpk, float* gdinv, int AM,
                                                int* rp_u, int* rp_s, int* grp,
                                                int N, int M) {
  int b = blockIdx.x, tid = threadIdx.x;
  int n = b == 0 ? N : M;
  int chunk = (n + 1023) / 1024;
  int lo = tid * chunk;
  int hi = lo + chunk < n ? lo + chunk : n;
  if (lo > n) lo = n;
  if (hi < lo) hi = lo;
  if (b == 0) {
    int s = 0;
    for (int i = lo; i < hi; ++i) s += (int)udeg[i];
    scan_core(s, rp_u, lo, hi, n, udeg, nullptr);
    for (int i = lo; i < hi; ++i) {
      float d = udeg[i];
      udeg[i] = d > 0.f ? rsqrtf(d) : 0.f;
    }
  } else if (b == 1) {
    int s = 0;
    for (int i = lo; i < hi; ++i) s += (int)sdeg[i];
    scan_core(s, rp_s, lo, hi, n, sdeg, nullptr);
    for (int i = lo; i < hi; ++i) {
      float d = sdeg[i];
      sdeg[i] = d > 0.f ? rsqrtf(d) : 0.f;
    }
  } else {
    int g = b - 2;
    const ull* pc = gpk + (size_t)g * AM;
    int s = 0;
    for (int i = lo; i < hi; ++i) s += (int)(pc[i] >> 40);
    scan_core(s, grp + (size_t)g * (M + 1), lo, hi, n, nullptr, pc);
    float* gd = gdinv + (size_t)g * AM;
    for (int i = lo; i < hi; ++i) {
      float d = (float)(pc[i] & PKMASK) * (1.0f / PKSCALE);
      gd[i] = d > 0.f ? rsqrtf(fmaxf(d, 1e-12f)) : 0.f;
    }
  }
}

// ---- both CSR fills in one dispatch ----
__global__ void k_allfill(const int* __restrict__ uu, const int* __restrict__ ss, int EUS,
                          const int* __restrict__ rp_u, const int* __restrict__ rp_s,
                          int* cur_u, int* cur_s, ushort* __restrict__ ue_s,
                          ushort* __restrict__ se_u, const int* __restrict__ ei1,
                          const int* __restrict__ ei2, const int* __restrict__ ei3,
                          const float* __restrict__ ew1, const float* __restrict__ ew2,
                          const float* __restrict__ ew3, int ES1, int ES2, int ES3,
                          const float* __restrict__ gdinv, const int* __restrict__ grp,
                          int* gcur, uint* __restrict__ gsrc, int M, int AM, int Etot) {
  int e = blockIdx.x * blockDim.x + threadIdx.x;
  if (e >= Etot) return;
  if (e < EUS) {
    int ui = uu[e], si = ss[e];
    int p = rp_u[ui] + atomicAdd(&cur_u[ui], 1);
    ue_s[p] = (ushort)si;
    int q = rp_s[si] + atomicAdd(&cur_s[si], 1);
    se_u[q] = (ushort)ui;
  } else {
    int t = e - EUS;
    const int* ei; const float* ew; int g, le, ESg, goff;
    if (t < ES1) { g = 0; le = t; ei = ei1; ew = ew1; ESg = ES1; goff = 0; }
    else if (t < ES1 + ES2) { g = 1; le = t - ES1; ei = ei2; ew = ew2; ESg = ES2; goff = ES1; }
    else { g = 2; le = t - ES1 - ES2; ei = ei3; ew = ew3; ESg = ES3; goff = ES1 + ES2; }
    int src = ei[le], dst = ei[ESg + le];
    float w = ew[le] * gdinv[(size_t)g * AM + src];
    int p = grp[(size_t)g * (M + 1) + dst] + atomicAdd(&gcur[(size_t)g * AM + dst], 1);
    gsrc[goff + p] = (uint)src | ((uint)f2h(w) << 16);
  }
}

// ---- pack f32 emb into dual-signal bf16 tables (sig1 = sig2 = emb) ----
__global__ void k_pack_dual(const float* __restrict__ ue, const float* __restrict__ se,
                            uint4* __restrict__ UC, uint4* __restrict__ SC, int N, int M) {
  int g = blockIdx.x * blockDim.x + threadIdx.x;
  int row = g >> 5, lane = g & 31;
  const float* src; uint4* dst; int r;
  if (row < N) { src = ue; dst = UC; r = row; }
  else if (row < N + M) { src = se; dst = SC; r = row - N; }
  else return;
  float4 v = ((const float4*)src)[(size_t)r * 32 + lane];
  uint a = bpack(v.x, v.y), b = bpack(v.z, v.w);
  dst[(size_t)r * 32 + lane] = make_uint4(a, b, a, b);
}

// ---- fused dual-signal bipartite layer: 64 lanes per row ----
__global__ void k_prop_dual(
    const int* __restrict__ rp_u, const ushort* __restrict__ ue_s,
    const int* __restrict__ rp_s, const ushort* __restrict__ se_u,
    const float* __restrict__ dinv_u, const float* __restrict__ dinv_s,
    const uint2* __restrict__ SCin, const uint2* __restrict__ UCin,
    uint2* __restrict__ SCout, uint2* __restrict__ UCout,
    const float* __restrict__ base_u1, const float* __restrict__ base_u2,
    const float* __restrict__ base_s1, const float* __restrict__ base_s2,
    float* __restrict__ acc_u1, float* __restrict__ acc_u2,
    float* __restrict__ acc_s1, float* __restrict__ acc_s2,
    float* dup_u2, float* dup_s2, float fs, int N, int M) {
  int g = blockIdx.x * blockDim.x + threadIdx.x;
  int row = g >> 6, l = g & 63;
  const int* rp; const ushort* ei; const float* dopp; const uint2* tbl;
  uint2* otbl; const float *b1, *b2; float *a1, *a2, *d2; float wrow; int r;
  if (row < N) {
    r = row; rp = rp_u; ei = ue_s; dopp = dinv_s; tbl = SCin; otbl = UCout;
    b1 = base_u1; b2 = base_u2; a1 = acc_u1; a2 = acc_u2; d2 = dup_u2;
    wrow = dinv_u[r];
  } else if (row < N + M) {
    r = row - N; rp = rp_s; ei = se_u; dopp = dinv_u; tbl = UCin; otbl = SCout;
    b1 = base_s1; b2 = base_s2; a1 = acc_s1; a2 = acc_s2; d2 = dup_s2;
    wrow = dinv_s[r];
  } else return;
  int beg = rp[r], end = rp[r + 1];
  float4 sum = make_float4(0.f, 0.f, 0.f, 0.f);
#pragma unroll 4
  for (int i = beg; i < end; ++i) {
    int idx = ei[i];
    float w = wrow * dopp[idx];
    uint2 v = tbl[(size_t)idx * 64 + l];
    sum.x = fmaf(w, blo(v.x), sum.x); sum.y = fmaf(w, bhi(v.x), sum.y);
    sum.z = fmaf(w, blo(v.y), sum.z); sum.w = fmaf(w, bhi(v.y), sum.w);
  }
  if (otbl)
    otbl[(size_t)r * 64 + l] = make_uint2(bpack(sum.x, sum.y), bpack(sum.z, sum.w));
  int j = l >> 1, sig = l & 1;
  size_t lf = (size_t)r * 32 + j;
  const float* b = sig ? b2 : b1;
  float* a = sig ? a2 : a1;
  float4 vb = ((const float4*)b)[lf];
  float4 o = make_float4((vb.x + sum.x) * fs, (vb.y + sum.y) * fs,
                         (vb.z + sum.z) * fs, (vb.w + sum.w) * fs);
  ((float4*)a)[lf] = o;
  if (sig && d2) ((float4*)d2)[lf] = o;
}

// ---- GCN gather, 64 lanes per row (2 dims/lane) ----
__global__ void k_gcn_gather(const int* __restrict__ rp, const uint* __restrict__ erec,
                             const float* __restrict__ dinv, const ushort* __restrict__ xw,
                             const float* __restrict__ base, float* __restrict__ out,
                             uint* outSC, float scale, int M) {
  int g = blockIdx.x * blockDim.x + threadIdx.x;
  int row = g >> 6, l = g & 63;
  if (row >= M) return;
  int beg = rp[row], end = rp[row + 1];
  const uint* sv = (const uint*)xw;  // 64 uints per row
  float2 sum = make_float2(0.f, 0.f);
#pragma unroll 4
  for (int i = beg; i < end; ++i) {
    uint rec = erec[i];
    int sr = rec & 0xffffu;
    float w = h2f((ushort)(rec >> 16));
    uint v = sv[(size_t)sr * 64 + l];
    sum.x = fmaf(w, blo(v), sum.x);
    sum.y = fmaf(w, bhi(v), sum.y);
  }
  float sc = dinv[row] * scale;
  size_t lf = (size_t)row * 64 + l;
  float2 b = ((const float2*)base)[lf];
  float2 o = make_float2(fmaf(sc, sum.x, b.x), fmaf(sc, sum.y, b.y));
  ((float2*)out)[lf] = o;
  if (outSC) outSC[(size_t)row * 128 + 4 * (l >> 1) + (l & 1)] = bpack(o.x, o.y);
}

// ---- GEMM: Y_bf16[rows x 128] = X[rows x 128] @ W[128 x 128] ----
struct DualHi { const uint4* p; };
__device__ __forceinline__ float4 ldx(const float* X, size_t i) {
  return ((const float4*)X)[i];
}
__device__ __forceinline__ float4 ldx(DualHi X, size_t i) {
  uint4 v = X.p[i];
  return make_float4(blo(v.z), bhi(v.z), blo(v.w), bhi(v.w));
}

template <typename XT>
__global__ __launch_bounds__(256) void k_gemm(XT X, const float* __restrict__ W,
                                              ushort* __restrict__ Y, int rows) {
  __shared__ float Wl[D * D];
  int tid = threadIdx.x;
  for (int i = tid; i < D * D / 4; i += 256) ((float4*)Wl)[i] = ((const float4*)W)[i];
  __syncthreads();
  int c = tid & 31, rg = tid >> 5;
  int r0 = blockIdx.x * 64;
  float4 acc[8];
#pragma unroll
  for (int j = 0; j < 8; ++j) acc[j] = make_float4(0.f, 0.f, 0.f, 0.f);
  for (int k4 = 0; k4 < 32; ++k4) {
    float4 xv[8];
#pragma unroll
    for (int j = 0; j < 8; ++j) {
      int r = r0 + rg + 8 * j;
      if (r >= rows) r = rows - 1;
      xv[j] = ldx(X, (size_t)r * 32 + k4);
    }
#pragma unroll
    for (int kk = 0; kk < 4; ++kk) {
      float4 wv = ((float4*)Wl)[(k4 * 4 + kk) * 32 + c];
#pragma unroll
      for (int j = 0; j < 8; ++j) {
        float xs = kk == 0 ? xv[j].x : kk == 1 ? xv[j].y : kk == 2 ? xv[j].z : xv[j].w;
        acc[j].x = fmaf(xs, wv.x, acc[j].x);
        acc[j].y = fmaf(xs, wv.y, acc[j].y);
        acc[j].z = fmaf(xs, wv.z, acc[j].z);
        acc[j].w = fmaf(xs, wv.w, acc[j].w);
      }
    }
  }
#pragma unroll
  for (int j = 0; j < 8; ++j) {
    int r = r0 + rg + 8 * j;
    if (r < rows)
      ((uint2*)(Y + (size_t)r * D))[c] =
          make_uint2(bpack(acc[j].x, acc[j].y), bpack(acc[j].z, acc[j].w));
  }
}

extern "C" void kernel_launch(void* const* d_in, const int* in_sizes, int n_in,
                              void* d_out, int out_size, void* d_ws, size_t ws_size,
                              hipStream_t stream) {
  const float* spot_emb = (const float*)d_in[0];
  const float* user_emb = (const float*)d_in[1];
  const float* W1 = (const float*)d_in[2];
  const float* W2 = (const float*)d_in[3];
  const float* W3 = (const float*)d_in[4];
  const float* ew1 = (const float*)d_in[5];
  const float* ew2 = (const float*)d_in[6];
  const float* ew3 = (const float*)d_in[7];
  const int* us = (const int*)d_in[8];
  const int* ei1 = (const int*)d_in[9];
  const int* ei2 = (const int*)d_in[10];
  const int* ei3 = (const int*)d_in[11];

  const int M = in_sizes[0] / D;
  const int N = in_sizes[1] / D;
  const int EUS = in_sizes[8] / 2;
  const int ES1 = in_sizes[9] / 2;
  const int ES2 = in_sizes[10] / 2;
  const int ES3 = in_sizes[11] / 2;
  const int EStot = ES1 + ES2 + ES3;
  const int Etot = EUS + EStot;

  const int* uu = us;
  const int* ss = us + EUS;

  const size_t MD = (size_t)M * D, ND = (size_t)N * D;
  const int AM = (int)((M + 63) & ~63);

  float* cur = (float*)d_ws;
  auto take = [&](size_t n) { float* p = cur; cur += (n + 63) & ~(size_t)63; return p; };

  // zero-group A: degree accumulators
  float* udeg = take(N);
  float* sdeg = take(M);
  ull* gpk = (ull*)take((size_t)6 * AM);
  float* zeroA_end = cur;
  // zero-group B: fill cursors
  int* cur_u = (int*)take(N);
  int* cur_s = (int*)take(M);
  int* gcur = (int*)take((size_t)3 * AM);
  float* zeroB_end = cur;
  float* gdinv = take((size_t)3 * AM);
  int* rp_u = (int*)take(N + 1);
  int* rp_s = (int*)take(M + 1);
  int* grp = (int*)take((size_t)3 * (M + 1));
  ushort* ue_s = (ushort*)take(EUS / 2 + 32);
  ushort* se_u = (ushort*)take(EUS / 2 + 32);
  uint* gsrc = (uint*)take(EStot);
  ushort* xw = (ushort*)take(MD / 2);
  uint2* UC_A = (uint2*)take(ND);
  uint2* UC_B = (uint2*)take(ND);
  uint2* SC_A = (uint2*)take(MD);
  uint2* SC_B = (uint2*)take(MD);

  float* out = (float*)d_out;
  float* o_so1 = out;
  float* o_uo1 = o_so1 + MD;
  float* o_so2 = o_uo1 + ND;
  float* o_uo2 = o_so2 + MD;
  float* o_so3 = o_uo2 + ND;
  float* o_uo3 = o_so3 + MD;

  const int B = 256;
  auto gr = [&](size_t work) { return (int)((work + B - 1) / B); };
  const int gProp = gr((size_t)(N + M) * 64);
  const int gM64 = gr((size_t)M * 64);
  const int gGemm = (M + 63) / 64;
  float* nulf = (float*)nullptr;

  hipMemsetAsync(udeg, 0, (char*)zeroA_end - (char*)udeg, stream);
  hipMemsetAsync(cur_u, 0, (char*)zeroB_end - (char*)cur_u, stream);

  // all degrees (bipartite + packed GCN) in one pass
  k_alldeg<<<gr(Etot), B, 0, stream>>>(uu, ss, EUS, ei1, ei2, ei3, ew1, ew2, ew3,
                                       ES1, ES2, ES3, udeg, sdeg, gpk, AM, Etot);
  // row pointers + all dinv transforms, one dispatch
  k_scan5<<<5, 1024, 0, stream>>>(udeg, sdeg, gpk, gdinv, AM, rp_u, rp_s, grp, N, M);
  // both CSR fills
  k_allfill<<<gr(Etot), B, 0, stream>>>(uu, ss, EUS, rp_u, rp_s, cur_u, cur_s, ue_s, se_u,
                                        ei1, ei2, ei3, ew1, ew2, ew3, ES1, ES2, ES3,
                                        gdinv, grp, gcur, gsrc, M, AM, Etot);
  // dual-signal bf16 tables
  k_pack_dual<<<gr((size_t)(N + M) * 32), B, 0, stream>>>(user_emb, spot_emb,
                                                          (uint4*)UC_A, (uint4*)SC_A, N, M);

  // branch-1 conv: o_so1 = spot_emb + cat1 (also writes SC_A sig1)
  k_gemm<<<gGemm, 256, 0, stream>>>(spot_emb, W1, xw, M);
  k_gcn_gather<<<gM64, B, 0, stream>>>(grp, gsrc, gdinv, xw, spot_emb, o_so1,
                                       (uint*)SC_A, 1.0f, M);

  // fused propagation: 3 layers, both signals
  k_prop_dual<<<gProp, B, 0, stream>>>(rp_u, ue_s, rp_s, se_u, udeg, sdeg,
                                       SC_A, UC_A, SC_B, UC_B,
                                       user_emb, user_emb, o_so1, spot_emb,
                                       o_uo1, o_uo2, o_so1, o_so2,
                                       nulf, nulf, 1.0f, N, M);
  k_prop_dual<<<gProp, B, 0, stream>>>(rp_u, ue_s, rp_s, se_u, udeg, sdeg,
                                       SC_B, UC_B, SC_A, UC_A,
                                       o_uo1, o_uo2, o_so1, o_so2,
                                       o_uo1, o_uo2, o_so1, o_so2,
                                       nulf, nulf, 1.0f, N, M);
  k_prop_dual<<<gProp, B, 0, stream>>>(rp_u, ue_s, rp_s, se_u, udeg, sdeg,
                                       SC_A, UC_A, SC_B, (uint2*)nullptr,
                                       o_uo1, o_uo2, o_so1, o_so2,
                                       o_uo1, o_uo2, o_so1, o_so2,
                                       o_uo3, o_so3, 0.25f, N, M);

  // branch 2: so2 += cat2/4
  k_gemm<<<gGemm, 256, 0, stream>>>(spot_emb, W2, xw, M);
  k_gcn_gather<<<gM64, B, 0, stream>>>(grp + (M + 1), gsrc + ES1, gdinv + AM, xw,
                                       o_so2, o_so2, (uint*)nullptr, 0.25f, M);

  // branch 3: so3 += cat3/4 (input fin_s = SC_B sig2)
  k_gemm<<<gGemm, 256, 0, stream>>>(DualHi{(const uint4*)SC_B}, W3, xw, M);
  k_gcn_gather<<<gM64, B, 0, stream>>>(grp + 2 * (M + 1), gsrc + ES1 + ES2,
                                       gdinv + 2 * AM, xw, o_so3, o_so3,
                                       (uint*)nullptr, 0.25f, M);
}